// Round 8
// baseline (1405.417 us; speedup 1.0000x reference)
//
#include <hip/hip_runtime.h>

#define N_NODES 100000
#define N_EDGES 1600000
#define IN_CH   128
#define HEADS   4
#define OUT_CH  32
#define HID     128   // HEADS*OUT_CH
#define NEG_SLOPE 0.2f

#define BNODES  256                       // nodes per bucket (pow2)
#define NBUCK   ((N_NODES + BNODES - 1) / BNODES)   // 391
#define NBLK    256                       // scatter blocks
#define EPB     (N_EDGES / NBLK)          // 6250 edges per block (exact)
#define BSLOT   4864                      // padded slots per bucket (mean 4096, +12 sigma)

typedef unsigned int  uint;
typedef unsigned short ushort;

// bf16 round-to-nearest-even pack
__device__ __forceinline__ ushort f2bf(float f) {
    uint u = __float_as_uint(f);
    return (ushort)((u + 0x7FFFu + ((u >> 16) & 1u)) >> 16);
}

// ---------------- K1: h = x @ W (fp32, bf16 store) + fused attention scores ----------------
// Exact R5 kernel (measured 78us, VGPR 88, 0 bank conflicts). Only change: bucket_cnt
// zero loop handles NBUCK=391 > 256.
#define BM 64
#define BK 32
__global__ __launch_bounds__(256) void k_gemm(const float* __restrict__ x,
                                              const float* __restrict__ w,
                                              const float* __restrict__ att,
                                              ushort* __restrict__ h,
                                              float* __restrict__ s_src,
                                              float* __restrict__ s_dst,
                                              int* __restrict__ bucket_cnt) {
    __shared__ float xsw[BK * BM];            // 8 KB, swizzled, [k][node] transposed
    __shared__ float wsld[BK][HID + 4];       // 16.9 KB

    const int tid = threadIdx.x;
    const int nodeBase = blockIdx.x * BM;
    const int q   = tid & 15;                 // channel quad id
    const int n0  = (tid >> 4) * 4;           // node sub-block base (0..60)
    const int cLo = q * 4;
    const int cHi = 64 + q * 4;

    // zero bucket reservation counters (k_scatter runs after us, stream-ordered)
    if (blockIdx.x == 0)
        for (int i = tid; i < NBUCK; i += 256) bucket_cnt[i] = 0;

    float acc[4][8];
#pragma unroll
    for (int i = 0; i < 4; i++)
#pragma unroll
        for (int j = 0; j < 8; j++) acc[i][j] = 0.0f;

    for (int k0 = 0; k0 < IN_CH; k0 += BK) {
        // ---- stage x (transposed + swizzled) ----
#pragma unroll
        for (int l = 0; l < 2; l++) {
            int idx  = tid + l * 256;
            int node = idx >> 3;              // 0..63
            int c4   = (idx & 7) * 4;         // k-col base
            int n = nodeBase + node;
            float4 v = make_float4(0.f, 0.f, 0.f, 0.f);
            if (n < N_NODES) v = *reinterpret_cast<const float4*>(x + (size_t)n * IN_CH + k0 + c4);
            int flip = (idx & 7) << 2;        // = ((c>>2)&7)<<2 for c = c4..c4+3
            float vv[4] = {v.x, v.y, v.z, v.w};
#pragma unroll
            for (int j = 0; j < 4; j++)
                xsw[(((c4 + j) << 6) + node) ^ flip] = vv[j];
        }
        // ---- stage w (contiguous 16B/lane) ----
#pragma unroll
        for (int l = 0; l < 4; l++) {
            int idx  = tid + l * 256;
            int row  = idx >> 5;              // 0..31
            int col4 = (idx & 31) * 4;
            float4 v = *reinterpret_cast<const float4*>(w + (size_t)(k0 + row) * HID + col4);
            *reinterpret_cast<float4*>(&wsld[row][col4]) = v;
        }
        __syncthreads();

#pragma unroll
        for (int kk = 0; kk < BK; kk++) {
            int flip = ((kk >> 2) & 7) << 2;
            float4 xv  = *reinterpret_cast<const float4*>(&xsw[((kk << 6) + n0) ^ flip]);
            float4 wlo = *reinterpret_cast<const float4*>(&wsld[kk][cLo]);
            float4 whi = *reinterpret_cast<const float4*>(&wsld[kk][cHi]);
            float xr[4] = {xv.x, xv.y, xv.z, xv.w};
            float wr[8] = {wlo.x, wlo.y, wlo.z, wlo.w, whi.x, whi.y, whi.z, whi.w};
#pragma unroll
            for (int i = 0; i < 4; i++)
#pragma unroll
                for (int j = 0; j < 8; j++)
                    acc[i][j] = fmaf(xr[i], wr[j], acc[i][j]);
        }
        __syncthreads();
    }

    // ---- epilogue: bf16 h store + fused scores ----
    const int head_lo = (tid >> 3) & 1;       // cLo's head (0 or 1)
    const int head_hi = head_lo + 2;          // cHi's head (2 or 3)
    const int cbase   = 4 * (tid & 7);        // channel offset within head
    float4 aslo = *reinterpret_cast<const float4*>(att + head_lo * 64 + cbase);
    float4 adlo = *reinterpret_cast<const float4*>(att + head_lo * 64 + 32 + cbase);
    float4 ashi = *reinterpret_cast<const float4*>(att + head_hi * 64 + cbase);
    float4 adhi = *reinterpret_cast<const float4*>(att + head_hi * 64 + 32 + cbase);

#pragma unroll
    for (int i = 0; i < 4; i++) {
        int n = nodeBase + n0 + i;
        bool ok = (n < N_NODES);
        if (ok) {
            uint2 plo, phi;
            plo.x = (uint)f2bf(acc[i][0]) | ((uint)f2bf(acc[i][1]) << 16);
            plo.y = (uint)f2bf(acc[i][2]) | ((uint)f2bf(acc[i][3]) << 16);
            phi.x = (uint)f2bf(acc[i][4]) | ((uint)f2bf(acc[i][5]) << 16);
            phi.y = (uint)f2bf(acc[i][6]) | ((uint)f2bf(acc[i][7]) << 16);
            *reinterpret_cast<uint2*>(h + (size_t)n * HID + cLo) = plo;
            *reinterpret_cast<uint2*>(h + (size_t)n * HID + cHi) = phi;
        }
        float sl_s = acc[i][0]*aslo.x + acc[i][1]*aslo.y + acc[i][2]*aslo.z + acc[i][3]*aslo.w;
        float sl_d = acc[i][0]*adlo.x + acc[i][1]*adlo.y + acc[i][2]*adlo.z + acc[i][3]*adlo.w;
        float sh_s = acc[i][4]*ashi.x + acc[i][5]*ashi.y + acc[i][6]*ashi.z + acc[i][7]*ashi.w;
        float sh_d = acc[i][4]*adhi.x + acc[i][5]*adhi.y + acc[i][6]*adhi.z + acc[i][7]*adhi.w;
        // reduce over the 8 threads (lane bits 0-2) sharing (node, head)
#pragma unroll
        for (int off = 1; off < 8; off <<= 1) {
            sl_s += __shfl_xor(sl_s, off);
            sl_d += __shfl_xor(sl_d, off);
            sh_s += __shfl_xor(sh_s, off);
            sh_d += __shfl_xor(sh_d, off);
        }
        if ((tid & 7) == 0 && ok) {
            s_src[n * HEADS + head_lo] = sl_s;
            s_dst[n * HEADS + head_lo] = sl_d;
            s_src[n * HEADS + head_hi] = sh_s;
            s_dst[n * HEADS + head_hi] = sh_d;
        }
    }
}

// ---------------- K2: bucket scatter (R5 scheme, 256-node buckets) ----------------
// LDS histogram -> one global reservation atomic per bucket -> scatter into the
// bucket's padded region. dst kept in 25 registers (single ei read per phase need).
__global__ __launch_bounds__(256) void k_scatter(const int* __restrict__ ei,
                                                 int* __restrict__ bucket_cnt,
                                                 int* __restrict__ packed) {
    __shared__ int cnt[NBUCK];
    __shared__ int cur[NBUCK];
    int t = threadIdx.x;
    for (int i = t; i < NBUCK; i += 256) cnt[i] = 0;
    __syncthreads();
    int base = blockIdx.x * EPB;
    int dreg[25];
#pragma unroll
    for (int j = 0; j < 25; j++) {
        bool ok = (j < 24) || (t < EPB - 24 * 256);   // EPB=6250 -> tail 106
        int e = base + t + j * 256;
        dreg[j] = ok ? ei[N_EDGES + e] : -1;
        if (ok) atomicAdd(&cnt[dreg[j] >> 8], 1);
    }
    __syncthreads();
    for (int i = t; i < NBUCK; i += 256) {
        int myBase = atomicAdd(&bucket_cnt[i], cnt[i]);   // device-scope reservation
        cur[i] = i * BSLOT + myBase;
    }
    __syncthreads();
#pragma unroll
    for (int j = 0; j < 25; j++) {
        bool ok = (j < 24) || (t < EPB - 24 * 256);
        if (ok) {
            int e = base + t + j * 256;
            int src = ei[e];
            int d   = dreg[j];
            int bkt = d >> 8;
            int pos = atomicAdd(&cur[bkt], 1);
            if (pos < (bkt + 1) * BSLOT)                  // safety clamp (P~0, fixed inputs)
                packed[pos] = (src << 8) | (d & (BNODES - 1));   // src<2^17 fits
        }
    }
}

// ---------------- K3: bucket-direct aggregation (replaces k_b2 + gather k_agg) ----------------
// One block per (bucket, head). All edges of a node are inside its bucket, so the
// block accumulates unnormalized sum_w and P*h in f32 LDS (atomic adds, channel
// order rotated by edge-slot -> all 32 banks hit -> 2-way max), then normalizes
// and writes out + bias. No CSR, no per-node sort, no row_start.
__global__ __launch_bounds__(256) void k_agg2(const int* __restrict__ packed,
                                              const int* __restrict__ bucket_cnt,
                                              const float* __restrict__ s_src,
                                              const float* __restrict__ s_dst,
                                              const ushort* __restrict__ h,
                                              const float* __restrict__ bias,
                                              float* __restrict__ out) {
    __shared__ float accS[BNODES * OUT_CH];   // 32 KB
    __shared__ float swS[BNODES];             // 1 KB
    __shared__ float sdS[BNODES];             // 1 KB

    const int b    = blockIdx.x >> 2;
    const int head = blockIdx.x & 3;
    const int tid  = threadIdx.x;
    const int q    = tid & 7;                 // channel sub-quad: ch = 4q..4q+3
    const int eIdx = tid >> 3;                // edge slot 0..31 (32 edges in flight)

    for (int i = tid; i < BNODES * OUT_CH; i += 256) accS[i] = 0.f;
    for (int i = tid; i < BNODES; i += 256) {
        swS[i] = 0.f;
        int n = b * BNODES + i;
        sdS[i] = (n < N_NODES) ? s_dst[n * HEADS + head] : 0.f;
    }
    __syncthreads();

    const int cntE = min(bucket_cnt[b], BSLOT);
    const int base = b * BSLOT;

    for (int e0 = 0; e0 < cntE; e0 += 32) {
        int e = e0 + eIdx;
        bool valid = e < cntE;
        int pk  = packed[base + (valid ? e : cntE - 1)];
        int src = pk >> 8;
        int dl  = pk & (BNODES - 1);
        float a = s_src[src * HEADS + head] + sdS[dl];
        a = fmaxf(a, NEG_SLOPE * a);                      // leaky relu
        float wgt = valid ? __expf(a) : 0.f;
        // 4 bf16 channels per lane: ch 4q..4q+3
        uint2 u = *reinterpret_cast<const uint2*>(h + (size_t)src * HID + head * OUT_CH + q * 4);
        float f[4];
        f[0] = __uint_as_float(u.x << 16);
        f[1] = __uint_as_float(u.x & 0xFFFF0000u);
        f[2] = __uint_as_float(u.y << 16);
        f[3] = __uint_as_float(u.y & 0xFFFF0000u);
        float* arow = &accS[dl * OUT_CH + q * 4];
#pragma unroll
        for (int jj = 0; jj < 4; jj++) {
            int j = (jj + eIdx) & 3;                      // rotate store order by edge slot
            atomicAdd(&arow[j], wgt * f[j]);
        }
        if (q == 0) atomicAdd(&swS[dl], wgt);
    }
    __syncthreads();

    // normalize + bias, coalesced write
    for (int i = tid; i < BNODES * OUT_CH; i += 256) {
        int nl = i >> 5, c = i & 31;
        int n = b * BNODES + nl;
        if (n < N_NODES) {
            float inv = 1.0f / (swS[nl] + 1e-16f);
            out[(size_t)n * HID + head * OUT_CH + c] = accS[i] * inv + bias[head * OUT_CH + c];
        }
    }
}

extern "C" void kernel_launch(void* const* d_in, const int* in_sizes, int n_in,
                              void* d_out, int out_size, void* d_ws, size_t ws_size,
                              hipStream_t stream) {
    const float* x    = (const float*)d_in[0];
    const int*   ei   = (const int*)  d_in[1];
    const float* w    = (const float*)d_in[2];
    const float* att  = (const float*)d_in[3];
    const float* bias = (const float*)d_in[4];
    float* out = (float*)d_out;

    char* p = (char*)d_ws;
    float* s_src    = (float*)p;  p += (size_t)N_NODES * HEADS * 4;        // 1.6 MB
    float* s_dst    = (float*)p;  p += (size_t)N_NODES * HEADS * 4;        // 1.6 MB
    ushort* h       = (ushort*)p; p += (size_t)N_NODES * HID * 2;          // 25.6 MB
    int* packed     = (int*)p;    p += (size_t)NBUCK * BSLOT * 4;          // 7.6 MB
    int* bucket_cnt = (int*)p;    p += (size_t)NBUCK * 4;

    k_gemm<<<(N_NODES + BM - 1) / BM, 256, 0, stream>>>(x, w, att, h, s_src, s_dst, bucket_cnt);
    k_scatter<<<NBLK, 256, 0, stream>>>(ei, bucket_cnt, packed);
    k_agg2<<<NBUCK * HEADS, 256, 0, stream>>>(packed, bucket_cnt, s_src, s_dst, h, bias, out);
}

// Round 9
// 356.270 us; speedup vs baseline: 3.9448x; 3.9448x over previous
//
#include <hip/hip_runtime.h>

#define N_NODES 100000
#define N_EDGES 1600000
#define IN_CH   128
#define HEADS   4
#define OUT_CH  32
#define HID     128   // HEADS*OUT_CH
#define NEG_SLOPE 0.2f

#define SLOT    64                        // padded edge slots per node (deg ~ Poisson(16), max ~45)

typedef unsigned int  uint;
typedef unsigned short ushort;

// bf16 round-to-nearest-even pack
__device__ __forceinline__ ushort f2bf(float f) {
    uint u = __float_as_uint(f);
    return (ushort)((u + 0x7FFFu + ((u >> 16) & 1u)) >> 16);
}

// ---------------- K1: h = x @ W (fp32, bf16 store) + fused attention scores ----------------
// Exact R5 kernel (measured 78us, VGPR 88, 0 bank conflicts). Each block zeroes the
// per-node degree counters for its own 64 nodes (k_fill runs after, stream-ordered).
#define BM 64
#define BK 32
__global__ __launch_bounds__(256) void k_gemm(const float* __restrict__ x,
                                              const float* __restrict__ w,
                                              const float* __restrict__ att,
                                              ushort* __restrict__ h,
                                              float* __restrict__ s_src,
                                              float* __restrict__ s_dst,
                                              int* __restrict__ cnt) {
    __shared__ float xsw[BK * BM];            // 8 KB, swizzled, [k][node] transposed
    __shared__ float wsld[BK][HID + 4];       // 16.9 KB

    const int tid = threadIdx.x;
    const int nodeBase = blockIdx.x * BM;
    const int q   = tid & 15;                 // channel quad id
    const int n0  = (tid >> 4) * 4;           // node sub-block base (0..60)
    const int cLo = q * 4;
    const int cHi = 64 + q * 4;

    // zero this block's degree counters
    if (tid < BM && nodeBase + tid < N_NODES) cnt[nodeBase + tid] = 0;

    float acc[4][8];
#pragma unroll
    for (int i = 0; i < 4; i++)
#pragma unroll
        for (int j = 0; j < 8; j++) acc[i][j] = 0.0f;

    for (int k0 = 0; k0 < IN_CH; k0 += BK) {
        // ---- stage x (transposed + swizzled) ----
#pragma unroll
        for (int l = 0; l < 2; l++) {
            int idx  = tid + l * 256;
            int node = idx >> 3;              // 0..63
            int c4   = (idx & 7) * 4;         // k-col base
            int n = nodeBase + node;
            float4 v = make_float4(0.f, 0.f, 0.f, 0.f);
            if (n < N_NODES) v = *reinterpret_cast<const float4*>(x + (size_t)n * IN_CH + k0 + c4);
            int flip = (idx & 7) << 2;        // = ((c>>2)&7)<<2 for c = c4..c4+3
            float vv[4] = {v.x, v.y, v.z, v.w};
#pragma unroll
            for (int j = 0; j < 4; j++)
                xsw[(((c4 + j) << 6) + node) ^ flip] = vv[j];
        }
        // ---- stage w (contiguous 16B/lane) ----
#pragma unroll
        for (int l = 0; l < 4; l++) {
            int idx  = tid + l * 256;
            int row  = idx >> 5;              // 0..31
            int col4 = (idx & 31) * 4;
            float4 v = *reinterpret_cast<const float4*>(w + (size_t)(k0 + row) * HID + col4);
            *reinterpret_cast<float4*>(&wsld[row][col4]) = v;
        }
        __syncthreads();

#pragma unroll
        for (int kk = 0; kk < BK; kk++) {
            int flip = ((kk >> 2) & 7) << 2;
            float4 xv  = *reinterpret_cast<const float4*>(&xsw[((kk << 6) + n0) ^ flip]);
            float4 wlo = *reinterpret_cast<const float4*>(&wsld[kk][cLo]);
            float4 whi = *reinterpret_cast<const float4*>(&wsld[kk][cHi]);
            float xr[4] = {xv.x, xv.y, xv.z, xv.w};
            float wr[8] = {wlo.x, wlo.y, wlo.z, wlo.w, whi.x, whi.y, whi.z, whi.w};
#pragma unroll
            for (int i = 0; i < 4; i++)
#pragma unroll
                for (int j = 0; j < 8; j++)
                    acc[i][j] = fmaf(xr[i], wr[j], acc[i][j]);
        }
        __syncthreads();
    }

    // ---- epilogue: bf16 h store + fused scores ----
    const int head_lo = (tid >> 3) & 1;       // cLo's head (0 or 1)
    const int head_hi = head_lo + 2;          // cHi's head (2 or 3)
    const int cbase   = 4 * (tid & 7);        // channel offset within head
    float4 aslo = *reinterpret_cast<const float4*>(att + head_lo * 64 + cbase);
    float4 adlo = *reinterpret_cast<const float4*>(att + head_lo * 64 + 32 + cbase);
    float4 ashi = *reinterpret_cast<const float4*>(att + head_hi * 64 + cbase);
    float4 adhi = *reinterpret_cast<const float4*>(att + head_hi * 64 + 32 + cbase);

#pragma unroll
    for (int i = 0; i < 4; i++) {
        int n = nodeBase + n0 + i;
        bool ok = (n < N_NODES);
        if (ok) {
            uint2 plo, phi;
            plo.x = (uint)f2bf(acc[i][0]) | ((uint)f2bf(acc[i][1]) << 16);
            plo.y = (uint)f2bf(acc[i][2]) | ((uint)f2bf(acc[i][3]) << 16);
            phi.x = (uint)f2bf(acc[i][4]) | ((uint)f2bf(acc[i][5]) << 16);
            phi.y = (uint)f2bf(acc[i][6]) | ((uint)f2bf(acc[i][7]) << 16);
            *reinterpret_cast<uint2*>(h + (size_t)n * HID + cLo) = plo;
            *reinterpret_cast<uint2*>(h + (size_t)n * HID + cHi) = phi;
        }
        float sl_s = acc[i][0]*aslo.x + acc[i][1]*aslo.y + acc[i][2]*aslo.z + acc[i][3]*aslo.w;
        float sl_d = acc[i][0]*adlo.x + acc[i][1]*adlo.y + acc[i][2]*adlo.z + acc[i][3]*adlo.w;
        float sh_s = acc[i][4]*ashi.x + acc[i][5]*ashi.y + acc[i][6]*ashi.z + acc[i][7]*ashi.w;
        float sh_d = acc[i][4]*adhi.x + acc[i][5]*adhi.y + acc[i][6]*adhi.z + acc[i][7]*adhi.w;
        // reduce over the 8 threads (lane bits 0-2) sharing (node, head)
#pragma unroll
        for (int off = 1; off < 8; off <<= 1) {
            sl_s += __shfl_xor(sl_s, off);
            sl_d += __shfl_xor(sl_d, off);
            sh_s += __shfl_xor(sh_s, off);
            sh_d += __shfl_xor(sh_d, off);
        }
        if ((tid & 7) == 0 && ok) {
            s_src[n * HEADS + head_lo] = sl_s;
            s_dst[n * HEADS + head_lo] = sl_d;
            s_src[n * HEADS + head_hi] = sh_s;
            s_dst[n * HEADS + head_hi] = sh_d;
        }
    }
}

// ---------------- K2: direct per-node edge fill (replaces scatter + b2) ----------------
// Maximal parallelism: every edge independent; one global atomic (memory-side, shared
// L3 -> no XCD bounce) + one 4B store into the node's padded 256B slot row.
__global__ __launch_bounds__(256) void k_fill(const int* __restrict__ ei,
                                              int* __restrict__ cnt,
                                              int* __restrict__ slots) {
    const int stride = gridDim.x * 256;
    for (int e = blockIdx.x * 256 + threadIdx.x; e < N_EDGES; e += stride) {
        int src = ei[e];
        int dst = ei[N_EDGES + e];
        int i = atomicAdd(&cnt[dst], 1);
        if (i < SLOT)                                    // P(deg>64) ~ 0; defensive clamp
            slots[(size_t)dst * SLOT + i] = src;
    }
}

// ---------------- K3: gather aggregation — one wave per node, 4 edges per iter ----------------
// R5-proven kernel (~73us, fabric-bound ~4 TB/s); reads the padded slot row directly.
__global__ __launch_bounds__(256) void k_agg(const int* __restrict__ cnt,
                                             const int* __restrict__ slots,
                                             const float* __restrict__ s_src,
                                             const float* __restrict__ s_dst,
                                             const ushort* __restrict__ h,
                                             const float* __restrict__ bias,
                                             float* __restrict__ out) {
    const int n    = blockIdx.x * 4 + (threadIdx.x >> 6);   // 4 nodes per block, 1 wave each
    const int lane = threadIdx.x & 63;
    const int g    = lane >> 4;          // edge sub-group 0..3
    const int q    = lane & 15;          // channel quad: ch = q*8 .. q*8+7
    const int head = q >> 2;             // 32 ch per head / 8 ch per quad

    const float sdh = s_dst[n * HEADS + head];
    const int deg = min(cnt[n], SLOT);
    const int beg = n * SLOT;
    const uint4* __restrict__ hrow = reinterpret_cast<const uint4*>(h);   // 16 uint4 per node row

    float acc[8];
#pragma unroll
    for (int k = 0; k < 8; k++) acc[k] = 0.f;
    float sum_w = 0.f;

#pragma unroll 2
    for (int j = 0; j < deg; j += 4) {
        int e = j + g;
        bool valid = e < deg;
        int src = slots[beg + (valid ? e : deg - 1)];    // clamp keeps load safe
        float ss = s_src[src * HEADS + head];            // L2-resident table
        uint4 u = hrow[(size_t)src * (HID / 8) + q];     // 16B = 8 bf16 channels
        float a = ss + sdh;
        a = fmaxf(a, NEG_SLOPE * a);                     // leaky relu
        float wgt = valid ? __expf(a) : 0.f;
        sum_w += wgt;
        uint uv[4] = {u.x, u.y, u.z, u.w};
#pragma unroll
        for (int t = 0; t < 4; t++) {
            acc[2 * t]     = fmaf(wgt, __uint_as_float(uv[t] << 16),        acc[2 * t]);
            acc[2 * t + 1] = fmaf(wgt, __uint_as_float(uv[t] & 0xFFFF0000u), acc[2 * t + 1]);
        }
    }

    // reduce the 4 edge-groups (lanes differing in bits 4,5)
#pragma unroll
    for (int k = 0; k < 8; k++) {
        acc[k] += __shfl_xor(acc[k], 16);
        acc[k] += __shfl_xor(acc[k], 32);
    }
    sum_w += __shfl_xor(sum_w, 16);
    sum_w += __shfl_xor(sum_w, 32);

    if (g == 0) {
        float inv = 1.0f / (sum_w + 1e-16f);
        int ch = q * 8;
        float4 b0 = *reinterpret_cast<const float4*>(bias + ch);
        float4 b1 = *reinterpret_cast<const float4*>(bias + ch + 4);
        float4 o0, o1;
        o0.x = acc[0] * inv + b0.x; o0.y = acc[1] * inv + b0.y;
        o0.z = acc[2] * inv + b0.z; o0.w = acc[3] * inv + b0.w;
        o1.x = acc[4] * inv + b1.x; o1.y = acc[5] * inv + b1.y;
        o1.z = acc[6] * inv + b1.z; o1.w = acc[7] * inv + b1.w;
        *reinterpret_cast<float4*>(out + (size_t)n * HID + ch)     = o0;
        *reinterpret_cast<float4*>(out + (size_t)n * HID + ch + 4) = o1;
    }
}

extern "C" void kernel_launch(void* const* d_in, const int* in_sizes, int n_in,
                              void* d_out, int out_size, void* d_ws, size_t ws_size,
                              hipStream_t stream) {
    const float* x    = (const float*)d_in[0];
    const int*   ei   = (const int*)  d_in[1];
    const float* w    = (const float*)d_in[2];
    const float* att  = (const float*)d_in[3];
    const float* bias = (const float*)d_in[4];
    float* out = (float*)d_out;

    char* p = (char*)d_ws;
    float* s_src = (float*)p;  p += (size_t)N_NODES * HEADS * 4;       // 1.6 MB
    float* s_dst = (float*)p;  p += (size_t)N_NODES * HEADS * 4;       // 1.6 MB
    ushort* h    = (ushort*)p; p += (size_t)N_NODES * HID * 2;         // 25.6 MB
    int* slots   = (int*)p;    p += (size_t)N_NODES * SLOT * 4;        // 25.6 MB
    int* cnt     = (int*)p;    p += (size_t)N_NODES * 4;               // 400 KB

    k_gemm<<<(N_NODES + BM - 1) / BM, 256, 0, stream>>>(x, w, att, h, s_src, s_dst, cnt);
    k_fill<<<2048, 256, 0, stream>>>(ei, cnt, slots);
    k_agg<<<N_NODES / 4, 256, 0, stream>>>(cnt, slots, s_src, s_dst, h, bias, out);
}

// Round 10
// 282.734 us; speedup vs baseline: 4.9708x; 1.2601x over previous
//
#include <hip/hip_runtime.h>

#define N_NODES 100000
#define N_EDGES 1600000
#define IN_CH   128
#define HEADS   4
#define OUT_CH  32
#define HID     128   // HEADS*OUT_CH
#define NEG_SLOPE 0.2f

#define BNODES  256                       // nodes per bucket (pow2)
#define NBUCK   ((N_NODES + BNODES - 1) / BNODES)   // 391
#define NBLK    256                       // scatter blocks
#define EPB     (N_EDGES / NBLK)          // 6250 edges per block (exact)
#define BSLOT   4864                      // padded slots per bucket (mean 4096, +12 sigma)

typedef unsigned int  uint;
typedef unsigned short ushort;

// bf16 round-to-nearest-even pack
__device__ __forceinline__ ushort f2bf(float f) {
    uint u = __float_as_uint(f);
    return (ushort)((u + 0x7FFFu + ((u >> 16) & 1u)) >> 16);
}

// ---------------- K1: h = x @ W (fp32, bf16 store) + fused attention scores ----------------
// Exact R5 kernel (measured 78us, VGPR 88, 0 bank conflicts).
#define BM 64
#define BK 32
__global__ __launch_bounds__(256) void k_gemm(const float* __restrict__ x,
                                              const float* __restrict__ w,
                                              const float* __restrict__ att,
                                              ushort* __restrict__ h,
                                              float* __restrict__ s_src,
                                              float* __restrict__ s_dst,
                                              int* __restrict__ bucket_cnt) {
    __shared__ float xsw[BK * BM];            // 8 KB, swizzled, [k][node] transposed
    __shared__ float wsld[BK][HID + 4];       // 16.9 KB

    const int tid = threadIdx.x;
    const int nodeBase = blockIdx.x * BM;
    const int q   = tid & 15;                 // channel quad id
    const int n0  = (tid >> 4) * 4;           // node sub-block base (0..60)
    const int cLo = q * 4;
    const int cHi = 64 + q * 4;

    // zero bucket reservation counters (k_scatter runs after us, stream-ordered)
    if (blockIdx.x == 0)
        for (int i = tid; i < NBUCK; i += 256) bucket_cnt[i] = 0;

    float acc[4][8];
#pragma unroll
    for (int i = 0; i < 4; i++)
#pragma unroll
        for (int j = 0; j < 8; j++) acc[i][j] = 0.0f;

    for (int k0 = 0; k0 < IN_CH; k0 += BK) {
        // ---- stage x (transposed + swizzled) ----
#pragma unroll
        for (int l = 0; l < 2; l++) {
            int idx  = tid + l * 256;
            int node = idx >> 3;              // 0..63
            int c4   = (idx & 7) * 4;         // k-col base
            int n = nodeBase + node;
            float4 v = make_float4(0.f, 0.f, 0.f, 0.f);
            if (n < N_NODES) v = *reinterpret_cast<const float4*>(x + (size_t)n * IN_CH + k0 + c4);
            int flip = (idx & 7) << 2;        // = ((c>>2)&7)<<2 for c = c4..c4+3
            float vv[4] = {v.x, v.y, v.z, v.w};
#pragma unroll
            for (int j = 0; j < 4; j++)
                xsw[(((c4 + j) << 6) + node) ^ flip] = vv[j];
        }
        // ---- stage w (contiguous 16B/lane) ----
#pragma unroll
        for (int l = 0; l < 4; l++) {
            int idx  = tid + l * 256;
            int row  = idx >> 5;              // 0..31
            int col4 = (idx & 31) * 4;
            float4 v = *reinterpret_cast<const float4*>(w + (size_t)(k0 + row) * HID + col4);
            *reinterpret_cast<float4*>(&wsld[row][col4]) = v;
        }
        __syncthreads();

#pragma unroll
        for (int kk = 0; kk < BK; kk++) {
            int flip = ((kk >> 2) & 7) << 2;
            float4 xv  = *reinterpret_cast<const float4*>(&xsw[((kk << 6) + n0) ^ flip]);
            float4 wlo = *reinterpret_cast<const float4*>(&wsld[kk][cLo]);
            float4 whi = *reinterpret_cast<const float4*>(&wsld[kk][cHi]);
            float xr[4] = {xv.x, xv.y, xv.z, xv.w};
            float wr[8] = {wlo.x, wlo.y, wlo.z, wlo.w, whi.x, whi.y, whi.z, whi.w};
#pragma unroll
            for (int i = 0; i < 4; i++)
#pragma unroll
                for (int j = 0; j < 8; j++)
                    acc[i][j] = fmaf(xr[i], wr[j], acc[i][j]);
        }
        __syncthreads();
    }

    // ---- epilogue: bf16 h store + fused scores ----
    const int head_lo = (tid >> 3) & 1;       // cLo's head (0 or 1)
    const int head_hi = head_lo + 2;          // cHi's head (2 or 3)
    const int cbase   = 4 * (tid & 7);        // channel offset within head
    float4 aslo = *reinterpret_cast<const float4*>(att + head_lo * 64 + cbase);
    float4 adlo = *reinterpret_cast<const float4*>(att + head_lo * 64 + 32 + cbase);
    float4 ashi = *reinterpret_cast<const float4*>(att + head_hi * 64 + cbase);
    float4 adhi = *reinterpret_cast<const float4*>(att + head_hi * 64 + 32 + cbase);

#pragma unroll
    for (int i = 0; i < 4; i++) {
        int n = nodeBase + n0 + i;
        bool ok = (n < N_NODES);
        if (ok) {
            uint2 plo, phi;
            plo.x = (uint)f2bf(acc[i][0]) | ((uint)f2bf(acc[i][1]) << 16);
            plo.y = (uint)f2bf(acc[i][2]) | ((uint)f2bf(acc[i][3]) << 16);
            phi.x = (uint)f2bf(acc[i][4]) | ((uint)f2bf(acc[i][5]) << 16);
            phi.y = (uint)f2bf(acc[i][6]) | ((uint)f2bf(acc[i][7]) << 16);
            *reinterpret_cast<uint2*>(h + (size_t)n * HID + cLo) = plo;
            *reinterpret_cast<uint2*>(h + (size_t)n * HID + cHi) = phi;
        }
        float sl_s = acc[i][0]*aslo.x + acc[i][1]*aslo.y + acc[i][2]*aslo.z + acc[i][3]*aslo.w;
        float sl_d = acc[i][0]*adlo.x + acc[i][1]*adlo.y + acc[i][2]*adlo.z + acc[i][3]*adlo.w;
        float sh_s = acc[i][4]*ashi.x + acc[i][5]*ashi.y + acc[i][6]*ashi.z + acc[i][7]*ashi.w;
        float sh_d = acc[i][4]*adhi.x + acc[i][5]*adhi.y + acc[i][6]*adhi.z + acc[i][7]*adhi.w;
        // reduce over the 8 threads (lane bits 0-2) sharing (node, head)
#pragma unroll
        for (int off = 1; off < 8; off <<= 1) {
            sl_s += __shfl_xor(sl_s, off);
            sl_d += __shfl_xor(sl_d, off);
            sh_s += __shfl_xor(sh_s, off);
            sh_d += __shfl_xor(sh_d, off);
        }
        if ((tid & 7) == 0 && ok) {
            s_src[n * HEADS + head_lo] = sl_s;
            s_dst[n * HEADS + head_lo] = sl_d;
            s_src[n * HEADS + head_hi] = sh_s;
            s_dst[n * HEADS + head_hi] = sh_d;
        }
    }
}

// ---------------- K2: bucket scatter (R5 reservation scheme, 256-node buckets) ----------------
// LDS histogram -> one global reservation atomic per bucket -> scatter into the
// bucket's padded region (dense per-block runs; this is the fast write pattern --
// R9's per-node direct fill bounced lines and ran 140us).
__global__ __launch_bounds__(256) void k_scatter(const int* __restrict__ ei,
                                                 int* __restrict__ bucket_cnt,
                                                 int* __restrict__ packed) {
    __shared__ int cnt[NBUCK];
    __shared__ int cur[NBUCK];
    int t = threadIdx.x;
    for (int i = t; i < NBUCK; i += 256) cnt[i] = 0;
    __syncthreads();
    int base = blockIdx.x * EPB;
    int dreg[25];
#pragma unroll
    for (int j = 0; j < 25; j++) {
        bool ok = (j < 24) || (t < EPB - 24 * 256);   // EPB=6250 -> tail 106
        int e = base + t + j * 256;
        dreg[j] = ok ? ei[N_EDGES + e] : -1;
        if (ok) atomicAdd(&cnt[dreg[j] >> 8], 1);
    }
    __syncthreads();
    for (int i = t; i < NBUCK; i += 256) {
        int myBase = atomicAdd(&bucket_cnt[i], cnt[i]);   // device-scope reservation
        cur[i] = i * BSLOT + myBase;
    }
    __syncthreads();
#pragma unroll
    for (int j = 0; j < 25; j++) {
        bool ok = (j < 24) || (t < EPB - 24 * 256);
        if (ok) {
            int e = base + t + j * 256;
            int src = ei[e];
            int d   = dreg[j];
            int bkt = d >> 8;
            int pos = atomicAdd(&cur[bkt], 1);
            if (pos < (bkt + 1) * BSLOT)                  // safety clamp (P~0, fixed inputs)
                packed[pos] = (src << 8) | (d & (BNODES - 1));   // src<2^17 fits
        }
    }
}

// ---------------- K3: per-bucket exact CSR + row_start (391 blocks, 1 node/thread) ----------
// BNODES=256: 2x the blocks of the R5 version (196 -> 391), ~4100 edges per block,
// full CU coverage. Same two-pass LDS-histogram structure otherwise.
__global__ __launch_bounds__(256) void k_b2(const int* __restrict__ packed,
                                            const int* __restrict__ bucket_cnt,
                                            int* __restrict__ csr_src,
                                            int* __restrict__ row_start) {
    __shared__ int cnt[BNODES];
    __shared__ int cur[BNODES];
    __shared__ int sm[256];
    __shared__ int smB[NBUCK + 1];
    const int b = blockIdx.x, t = threadIdx.x;

    // tight output base = exclusive prefix of bucket_cnt over buckets < b
    for (int i = t; i < NBUCK; i += 256) smB[i] = bucket_cnt[i];
    cnt[t] = 0;
    __syncthreads();
    // serial-ish prefix over 391 entries done cooperatively: simple Hillis-Steele on 512 padded
    // (NBUCK=391 < 512). Use sm as scratch in two stages of 256.
    // Cheap approach: thread 0..? -- do it with a single wave to keep it simple & correct.
    if (t == 0) {
        int run = 0;
        for (int i = 0; i < NBUCK; i++) { int v = smB[i]; smB[i] = run; run += v; }
        smB[NBUCK] = run;
    }
    __syncthreads();
    const int myCnt     = bucket_cnt[b];
    const int tight_beg = smB[b];
    const int beg_pad   = b * BSLOT;
    const int end_pad   = beg_pad + myCnt;

    // pass 1: per-node counts
    for (int e = beg_pad + t; e < end_pad; e += 256)
        atomicAdd(&cnt[packed[e] & (BNODES - 1)], 1);
    __syncthreads();

    int c0 = cnt[t];
    sm[t] = c0;
    __syncthreads();
    for (int off = 1; off < 256; off <<= 1) {
        int v = (t >= off) ? sm[t - off] : 0;
        __syncthreads();
        sm[t] += v;
        __syncthreads();
    }
    int p0 = tight_beg + sm[t] - c0;
    cur[t] = p0;
    int node = b * BNODES + t;
    if (node <= N_NODES) row_start[node] = p0;
    // last block also closes the array (node N_NODES may fall beyond last bucket's range)
    if (b == NBUCK - 1 && t == 255) row_start[N_NODES] = tight_beg + sm[255];
    __syncthreads();

    // pass 2: scatter srcs
    for (int e = beg_pad + t; e < end_pad; e += 256) {
        int pk = packed[e];
        int pos = atomicAdd(&cur[pk & (BNODES - 1)], 1);
        csr_src[pos] = pk >> 8;
    }
}

// ---------------- K4: gather aggregation — one wave per node, 4 edges per iter ----------------
// R5-proven kernel (~73us, fabric-bound ~4 TB/s).
__global__ __launch_bounds__(256) void k_agg(const int* __restrict__ row_start,
                                             const int* __restrict__ csr_src,
                                             const float* __restrict__ s_src,
                                             const float* __restrict__ s_dst,
                                             const ushort* __restrict__ h,
                                             const float* __restrict__ bias,
                                             float* __restrict__ out) {
    const int n    = blockIdx.x * 4 + (threadIdx.x >> 6);   // 4 nodes per block, 1 wave each
    const int lane = threadIdx.x & 63;
    const int g    = lane >> 4;          // edge sub-group 0..3
    const int q    = lane & 15;          // channel quad: ch = q*8 .. q*8+7
    const int head = q >> 2;             // 32 ch per head / 8 ch per quad

    const float sdh = s_dst[n * HEADS + head];
    const int beg = row_start[n], end = row_start[n + 1];
    const uint4* __restrict__ hrow = reinterpret_cast<const uint4*>(h);   // 16 uint4 per node row

    float acc[8];
#pragma unroll
    for (int k = 0; k < 8; k++) acc[k] = 0.f;
    float sum_w = 0.f;

#pragma unroll 2
    for (int j = beg; j < end; j += 4) {
        int e = j + g;
        bool valid = e < end;
        int src = csr_src[valid ? e : end - 1];          // clamp keeps load safe
        float ss = s_src[src * HEADS + head];            // L2-resident table
        uint4 u = hrow[(size_t)src * (HID / 8) + q];     // 16B = 8 bf16 channels
        float a = ss + sdh;
        a = fmaxf(a, NEG_SLOPE * a);                     // leaky relu
        float wgt = valid ? __expf(a) : 0.f;
        sum_w += wgt;
        uint uv[4] = {u.x, u.y, u.z, u.w};
#pragma unroll
        for (int t = 0; t < 4; t++) {
            acc[2 * t]     = fmaf(wgt, __uint_as_float(uv[t] << 16),        acc[2 * t]);
            acc[2 * t + 1] = fmaf(wgt, __uint_as_float(uv[t] & 0xFFFF0000u), acc[2 * t + 1]);
        }
    }

    // reduce the 4 edge-groups (lanes differing in bits 4,5)
#pragma unroll
    for (int k = 0; k < 8; k++) {
        acc[k] += __shfl_xor(acc[k], 16);
        acc[k] += __shfl_xor(acc[k], 32);
    }
    sum_w += __shfl_xor(sum_w, 16);
    sum_w += __shfl_xor(sum_w, 32);

    if (g == 0) {
        float inv = 1.0f / (sum_w + 1e-16f);
        int ch = q * 8;
        float4 b0 = *reinterpret_cast<const float4*>(bias + ch);
        float4 b1 = *reinterpret_cast<const float4*>(bias + ch + 4);
        float4 o0, o1;
        o0.x = acc[0] * inv + b0.x; o0.y = acc[1] * inv + b0.y;
        o0.z = acc[2] * inv + b0.z; o0.w = acc[3] * inv + b0.w;
        o1.x = acc[4] * inv + b1.x; o1.y = acc[5] * inv + b1.y;
        o1.z = acc[6] * inv + b1.z; o1.w = acc[7] * inv + b1.w;
        *reinterpret_cast<float4*>(out + (size_t)n * HID + ch)     = o0;
        *reinterpret_cast<float4*>(out + (size_t)n * HID + ch + 4) = o1;
    }
}

extern "C" void kernel_launch(void* const* d_in, const int* in_sizes, int n_in,
                              void* d_out, int out_size, void* d_ws, size_t ws_size,
                              hipStream_t stream) {
    const float* x    = (const float*)d_in[0];
    const int*   ei   = (const int*)  d_in[1];
    const float* w    = (const float*)d_in[2];
    const float* att  = (const float*)d_in[3];
    const float* bias = (const float*)d_in[4];
    float* out = (float*)d_out;

    char* p = (char*)d_ws;
    float* s_src    = (float*)p;  p += (size_t)N_NODES * HEADS * 4;        // 1.6 MB
    float* s_dst    = (float*)p;  p += (size_t)N_NODES * HEADS * 4;        // 1.6 MB
    ushort* h       = (ushort*)p; p += (size_t)N_NODES * HID * 2;          // 25.6 MB
    int* csr_src    = (int*)p;    p += (size_t)N_EDGES * 4;                // 6.4 MB
    int* packed     = (int*)p;    p += (size_t)NBUCK * BSLOT * 4;          // 7.6 MB
    int* row_start  = (int*)p;    p += (size_t)(N_NODES + 1) * 4;
    int* bucket_cnt = (int*)p;    p += (size_t)NBUCK * 4;

    k_gemm<<<(N_NODES + BM - 1) / BM, 256, 0, stream>>>(x, w, att, h, s_src, s_dst, bucket_cnt);
    k_scatter<<<NBLK, 256, 0, stream>>>(ei, bucket_cnt, packed);
    k_b2<<<NBUCK, 256, 0, stream>>>(packed, bucket_cnt, csr_src, row_start);
    k_agg<<<N_NODES / 4, 256, 0, stream>>>(row_start, csr_src, s_src, s_dst, h, bias, out);
}